// Round 20
// baseline (644.418 us; speedup 1.0000x reference)
//
#include <hip/hip_runtime.h>
#include <hip/hip_bf16.h>

#define DEV_INLINE __device__ __forceinline__

typedef short s16x8 __attribute__((ext_vector_type(8)));
typedef float f32x4 __attribute__((ext_vector_type(4)));

DEV_INLINE float gelu_exact(float x) {
    return 0.5f * x * (1.0f + erff(x * 0.70710678118654752440f));
}
DEV_INLINE double gelu64(double x) {
    return 0.5 * x * (1.0 + erf(x * 0.70710678118654752440));
}
DEV_INLINE unsigned short f2bf_rne(float f) {
    unsigned u = __float_as_uint(f);
    unsigned r = u + 0x7FFFu + ((u >> 16) & 1u);
    return (unsigned short)(r >> 16);
}
DEV_INLINE float bf2f(unsigned short h) { return __uint_as_float(((unsigned)h) << 16); }

DEV_INLINE void gload_lds16(const void* g, void* l) {
    __builtin_amdgcn_global_load_lds(
        (const __attribute__((address_space(1))) unsigned int*)g,
        (__attribute__((address_space(3))) unsigned int*)l, 16, 0, 0);
}

DEV_INLINE unsigned med3u32(unsigned a, unsigned b, unsigned c) {
    unsigned d;
    asm("v_med3_u32 %0, %1, %2, %3" : "=v"(d) : "v"(a), "v"(b), "v"(c));
    return d;
}

// ---------------- conv1 (f64): ts (16,100,2048) f32 -> relu(causal conv d=1) -> h1 (16,64,2048) f64
__global__ __launch_bounds__(256) void conv1_kernel64(
    const float* __restrict__ x, const float* __restrict__ w,
    const float* __restrict__ bias, double* __restrict__ y)
{
    const int b = blockIdx.y;
    const int t0 = blockIdx.x * 32;
    __shared__ double xs[100][34];
    for (int e = threadIdx.x; e < 100 * 34; e += 256) {
        int i = e / 34, u = e - i * 34;
        int t = t0 - 2 + u;
        xs[i][u] = (t >= 0) ? (double)x[(b * 100 + i) * 2048 + t] : 0.0;
    }
    __syncthreads();
    const int o = threadIdx.x & 63;
    const int ts = (threadIdx.x >> 6) * 8;
    double acc[8];
    double bv = (double)bias[o];
#pragma unroll
    for (int j = 0; j < 8; ++j) acc[j] = bv;
    const float* wo = w + o * 300;
    for (int i = 0; i < 100; ++i) {
        double w0 = (double)wo[i * 3 + 0], w1 = (double)wo[i * 3 + 1], w2 = (double)wo[i * 3 + 2];
#pragma unroll
        for (int j = 0; j < 8; ++j) {
            acc[j] = fma(w0, xs[i][ts + j],
                     fma(w1, xs[i][ts + j + 1],
                     fma(w2, xs[i][ts + j + 2], acc[j])));
        }
    }
#pragma unroll
    for (int j = 0; j < 8; ++j)
        y[(b * 64 + o) * 2048 + t0 + ts + j] = fmax(acc[j], 0.0);
}

// ---------------- conv2 (f64): h1 -> relu(causal conv d=2) -> xt64 (16,2048,128) transposed
__global__ __launch_bounds__(256) void conv2_kernel64(
    const double* __restrict__ x, const float* __restrict__ w,
    const float* __restrict__ bias, double* __restrict__ xt)
{
    const int b = blockIdx.y;
    const int t0 = blockIdx.x * 32;
    __shared__ double xs[64][36];
    for (int e = threadIdx.x; e < 64 * 36; e += 256) {
        int i = e / 36, u = e - i * 36;
        int t = t0 - 4 + u;
        xs[i][u] = (t >= 0) ? x[(b * 64 + i) * 2048 + t] : 0.0;
    }
    __syncthreads();
    const int o = threadIdx.x & 127;
    const int ts = (threadIdx.x >> 7) * 16;
    double acc[16];
    double bv = (double)bias[o];
#pragma unroll
    for (int j = 0; j < 16; ++j) acc[j] = bv;
    const float* wo = w + o * 192;
    for (int i = 0; i < 64; ++i) {
        double w0 = (double)wo[i * 3 + 0], w1 = (double)wo[i * 3 + 1], w2 = (double)wo[i * 3 + 2];
#pragma unroll
        for (int j = 0; j < 16; ++j) {
            acc[j] = fma(w0, xs[i][ts + j],
                     fma(w1, xs[i][ts + j + 2],
                     fma(w2, xs[i][ts + j + 4], acc[j])));
        }
    }
#pragma unroll
    for (int j = 0; j < 16; ++j)
        xt[(size_t)(b * 2048 + t0 + ts + j) * 128 + o] = fmax(acc[j], 0.0);
}

// ---------------- norm+split: xt64 -> f64-normalized rows (XN64, SQ64) + hi/mid bf16 planes
// NOTE: XN64 may alias xt64 (in-place): each element is read only by the thread that writes it.
__global__ __launch_bounds__(256) void norm_planes_kernel(
    const double* __restrict__ xt64, unsigned short* __restrict__ XH,
    unsigned short* __restrict__ XM, double* __restrict__ XN64,
    double* __restrict__ SQ64)
{
    const int row = blockIdx.x * 4 + (threadIdx.x >> 6);
    const int lane = threadIdx.x & 63;
    double v0 = xt64[(size_t)row * 128 + lane * 2];
    double v1 = xt64[(size_t)row * 128 + lane * 2 + 1];
    double s = v0 * v0 + v1 * v1;
#pragma unroll
    for (int off = 32; off > 0; off >>= 1) s += __shfl_xor(s, off);
    double inv = 1.0 / fmax(sqrt(s), 1e-12);
    double n0 = v0 * inv, n1 = v1 * inv;
    XN64[(size_t)row * 128 + lane * 2]     = n0;
    XN64[(size_t)row * 128 + lane * 2 + 1] = n1;
    double q = n0 * n0 + n1 * n1;
#pragma unroll
    for (int off = 32; off > 0; off >>= 1) q += __shfl_xor(q, off);
    if (lane == 0) SQ64[row] = q;
    float x0 = (float)n0, x1 = (float)n1;
    unsigned short h0 = f2bf_rne(x0), h1 = f2bf_rne(x1);
    unsigned short m0 = f2bf_rne(x0 - bf2f(h0)), m1 = f2bf_rne(x1 - bf2f(h1));
    ushort2 hv; hv.x = h0; hv.y = h1;
    ushort2 mv; mv.x = m0; mv.y = m1;
    *(ushort2*)(XH + (size_t)row * 128 + lane * 2) = hv;
    *(ushort2*)(XM + (size_t)row * 128 + lane * 2) = mv;
}

// sorted-insert via med3: for sorted k0>=...>=k8 and candidate c,
// k0' = max(k0,c); ki' = median(k_{i-1}, k_i, c). 9 independent ops.
#define INS9(cc) do { \
    unsigned c_ = (cc); \
    unsigned n0_ = (k0 > c_) ? k0 : c_; \
    unsigned n1_ = med3u32(k0, k1, c_); \
    unsigned n2_ = med3u32(k1, k2, c_); \
    unsigned n3_ = med3u32(k2, k3, c_); \
    unsigned n4_ = med3u32(k3, k4, c_); \
    unsigned n5_ = med3u32(k4, k5, c_); \
    unsigned n6_ = med3u32(k5, k6, c_); \
    unsigned n7_ = med3u32(k6, k7, c_); \
    unsigned n8_ = med3u32(k7, k8, c_); \
    k0 = n0_; k1 = n1_; k2 = n2_; k3 = n3_; k4 = n4_; \
    k5 = n5_; k6 = n6_; k7 = n7_; k8 = n8_; \
} while (0)

// ---------------- knn stage 1 v11: 4-wave blocks (256 thr), 64 A-rows/block ->
// grid 1024 = 4 blocks/CU (two independent barrier domains per CU). Same MFMA/
// selection structure as v10; staging split: plane p=wave>>1, half=wave&1.
__global__ __launch_bounds__(256, 4) void knn_mfma11_kernel(
    const unsigned short* __restrict__ XH, const unsigned short* __restrict__ XM,
    int* __restrict__ cand_out)
{
    __shared__ __align__(16) unsigned char smem[32768];  // 2 bufs x (H 8KB | M 8KB)

    const int tid = threadIdx.x, wave = tid >> 6, lane = tid & 63;
    const int bid = blockIdx.x;
    const int j = bid >> 3;                      // 0..127
    const int b = (bid & 7) * 2 + (j >> 6);      // XCD-local batch
    const int rest = j & 63;
    const int ntile = rest >> 1;                 // 0..31
    const int mhalf = rest & 1;                  // 0..1
    const int n0 = ntile * 64;
    const int mstart = mhalf * 1024;
    const unsigned short* Hb = XH + (size_t)b * 2048 * 128;
    const unsigned short* Mb = XM + (size_t)b * 2048 * 128;

    s16x8 aH[4], aM[4];
    {
        int arow = n0 + wave * 16 + (lane & 15);
        const unsigned short* hrow = Hb + (size_t)arow * 128;
        const unsigned short* mrow = Mb + (size_t)arow * 128;
        int cb = (lane >> 4) * 8;
#pragma unroll
        for (int s = 0; s < 4; ++s) {
            aH[s] = *(const s16x8*)(hrow + s * 32 + cb);
            aM[s] = *(const s16x8*)(mrow + s * 32 + cb);
        }
    }

    // staging: 32-row tiles; per wave: plane p=wave>>1, half=wave&1;
    // descriptors c in 0..3: r = half*16 + c*4 + (lane>>4); inverse-swizzled col.
    const unsigned short* Pb = (wave >> 1) ? Mb : Hb;
    const unsigned short* gsrc0; const unsigned short* gsrc1;
    const unsigned short* gsrc2; const unsigned short* gsrc3;
    {
        int half = wave & 1;
        int r0 = half * 16 + 0 + (lane >> 4), c0 = (lane & 15) ^ (r0 & 7);
        int r1 = half * 16 + 4 + (lane >> 4), c1 = (lane & 15) ^ (r1 & 7);
        int r2 = half * 16 + 8 + (lane >> 4), c2 = (lane & 15) ^ (r2 & 7);
        int r3 = half * 16 + 12 + (lane >> 4), c3 = (lane & 15) ^ (r3 & 7);
        gsrc0 = Pb + (size_t)(mstart + r0) * 128 + c0 * 8;
        gsrc1 = Pb + (size_t)(mstart + r1) * 128 + c1 * 8;
        gsrc2 = Pb + (size_t)(mstart + r2) * 128 + c2 * 8;
        gsrc3 = Pb + (size_t)(mstart + r3) * 128 + c3 * 8;
    }
    const unsigned ldsbase = (wave >> 1) * 8192 + (wave & 1) * 4096;

    unsigned k0 = 0, k1 = 0, k2 = 0, k3 = 0, k4 = 0, k5 = 0, k6 = 0, k7 = 0, k8 = 0;

    gload_lds16(gsrc0, smem + ldsbase);
    gload_lds16(gsrc1, smem + ldsbase + 1024);
    gload_lds16(gsrc2, smem + ldsbase + 2048);
    gload_lds16(gsrc3, smem + ldsbase + 3072);
    __syncthreads();

    int cur = 0;
    for (int t = 0; t < 32; ++t) {
        if (t < 31) {
            size_t go = (size_t)(t + 1) * 32 * 128;
            unsigned lb = (cur ^ 1) * 16384 + ldsbase;
            gload_lds16(gsrc0 + go, smem + lb);
            gload_lds16(gsrc1 + go, smem + lb + 1024);
            gload_lds16(gsrc2 + go, smem + lb + 2048);
            gload_lds16(gsrc3 + go, smem + lb + 3072);
        }
        const unsigned char* B0 = smem + cur * 16384;
        const unsigned char* B1 = B0 + 8192;
#pragma unroll
        for (int ct = 0; ct < 2; ++ct) {
            f32x4 accA; accA[0] = 0.f; accA[1] = 0.f; accA[2] = 0.f; accA[3] = 0.f;
            f32x4 accB; accB[0] = 0.f; accB[1] = 0.f; accB[2] = 0.f; accB[3] = 0.f;
            int r = ct * 16 + (lane & 15);
#pragma unroll
            for (int s = 0; s < 4; ++s) {
                int off = r * 256 + (((s * 64) + ((lane >> 4) * 16)) ^ ((r & 7) << 4));
                s16x8 bH = *(const s16x8*)(B0 + off);
                s16x8 bM = *(const s16x8*)(B1 + off);
                accA = __builtin_amdgcn_mfma_f32_16x16x32_bf16(bH, aH[s], accA, 0, 0, 0);
                accB = __builtin_amdgcn_mfma_f32_16x16x32_bf16(bM, aH[s], accB, 0, 0, 0);
                accB = __builtin_amdgcn_mfma_f32_16x16x32_bf16(bH, aM[s], accB, 0, 0, 0);
            }
            // within-lane candidate id = t*8 + ct*4 + reg (256 total, ascending m)
            const unsigned Lb = (unsigned)(255 - (t * 8 + ct * 4));
            unsigned key0 = (__float_as_uint(accA[0] + accB[0] + 2.0f) & 0xFFFFFF00u) | (Lb - 0u);
            unsigned key1 = (__float_as_uint(accA[1] + accB[1] + 2.0f) & 0xFFFFFF00u) | (Lb - 1u);
            unsigned key2 = (__float_as_uint(accA[2] + accB[2] + 2.0f) & 0xFFFFFF00u) | (Lb - 2u);
            unsigned key3 = (__float_as_uint(accA[3] + accB[3] + 2.0f) & 0xFFFFFF00u) | (Lb - 3u);
            INS9(key0);
            INS9(key1);
            INS9(key2);
            INS9(key3);
        }
        __syncthreads();
        cur ^= 1;
    }

    const int g = lane >> 4;
    const int row = b * 2048 + n0 + wave * 16 + (lane & 15);
#pragma unroll
    for (int pass = 0; pass < 16; ++pass) {
        unsigned mykey = k0;
        int L = 255 - (int)(mykey & 0xFFu);
        int mym = mstart + (L >> 3) * 32 + ((L >> 2) & 1) * 16 + g * 4 + (L & 3);
        unsigned bkey = mykey; int bm = mym;
        unsigned ok = (unsigned)__shfl_xor((int)bkey, 16); int om = __shfl_xor(bm, 16);
        bool tk = (ok > bkey) || (ok == bkey && om < bm);
        bkey = tk ? ok : bkey; bm = tk ? om : bm;
        ok = (unsigned)__shfl_xor((int)bkey, 32); om = __shfl_xor(bm, 32);
        tk = (ok > bkey) || (ok == bkey && om < bm);
        bkey = tk ? ok : bkey; bm = tk ? om : bm;
        if (mym == bm) {
            k0 = k1; k1 = k2; k2 = k3; k3 = k4; k4 = k5; k5 = k6; k6 = k7; k7 = k8; k8 = 0;
        }
        if (g == (pass & 3)) cand_out[(size_t)row * 32 + mhalf * 16 + pass] = bm;
    }
}

// ---------------- knn stage 2 v5 (f64): coalesced rescore + rank-by-count selection.
// (256,4): VGPR cap 128; ~60 live regs, NO spill (round-18 lesson).
__global__ __launch_bounds__(256, 4) void rescore5_kernel(
    const double* __restrict__ XN64, const double* __restrict__ SQ64,
    const int* __restrict__ cand, int* __restrict__ idx_out)
{
    const int wid = threadIdx.x >> 6, lane = threadIdx.x & 63;
    const int wb = (blockIdx.x & 7) * 1024 + (blockIdx.x >> 3);  // 8192 blocks, bijective
    const int n = wb * 4 + wid;
    const int b = n >> 11;
    const int g = lane >> 4, e = lane & 15;
    const double* Xb = XN64 + (size_t)(b * 2048) * 128;
    const double* SQb = SQ64 + (size_t)b * 2048;

    double2 xq[4];
    const double* xqp = XN64 + (size_t)n * 128;
#pragma unroll
    for (int it = 0; it < 4; ++it)
        xq[it] = *(const double2*)(xqp + it * 32 + e * 2);

    int mi[8];
    double s[8];
#pragma unroll
    for (int bb = 0; bb < 8; ++bb) {
        int m = cand[(size_t)n * 32 + bb * 4 + g];
        mi[bb] = m;
        const double* xm = Xb + (size_t)m * 128;
        double a0 = 0.0, a1 = 0.0;
#pragma unroll
        for (int it = 0; it < 4; ++it) {
            double2 v = *(const double2*)(xm + it * 32 + e * 2);
            a0 = fma(xq[it].x, v.x, a0);
            a1 = fma(xq[it].y, v.y, a1);
        }
        s[bb] = a0 + a1;
    }
#pragma unroll
    for (int bb = 0; bb < 8; ++bb) {
        double d = s[bb];
        d += __shfl_xor(d, 1);
        d += __shfl_xor(d, 2);
        d += __shfl_xor(d, 4);
        d += __shfl_xor(d, 8);
        s[bb] = 2.0 * d - SQb[mi[bb]];
    }
    double mys = s[0]; int mym = mi[0];
#pragma unroll
    for (int q = 1; q < 8; ++q) {
        bool p = (e == q);
        mys = p ? s[q] : mys;
        mym = p ? mi[q] : mym;
    }
    int cnt = 0;
#pragma unroll
    for (int bb = 0; bb < 8; ++bb) {
        cnt += ((s[bb] > mys) || (s[bb] == mys && mi[bb] < mym)) ? 1 : 0;
        double a16 = __shfl_xor(s[bb], 16); int m16 = __shfl_xor(mi[bb], 16);
        cnt += ((a16 > mys) || (a16 == mys && m16 < mym)) ? 1 : 0;
        double a32 = __shfl_xor(s[bb], 32); int m32 = __shfl_xor(mi[bb], 32);
        cnt += ((a32 > mys) || (a32 == mys && m32 < mym)) ? 1 : 0;
        double a48 = __shfl_xor(a16, 32);  int m48 = __shfl_xor(m16, 32);
        cnt += ((a48 > mys) || (a48 == mys && m48 < mym)) ? 1 : 0;
    }
    if (e < 8 && cnt < 9)
        idx_out[(size_t)n * 9 + cnt] = mym;
}

// ---------------- f64 GEMM v2 (mode 0 only): K=128 in 4 chunks of 32, 34.8 KB LDS,
// 4 blocks/CU, vectorized staging.
__global__ __launch_bounds__(256, 4) void gemm64t0_kernel(
    const double* __restrict__ A, const float* __restrict__ W,
    double* __restrict__ out)
{
    __shared__ double As[64][34];
    __shared__ double Ws[64][34];
    const int bx = (blockIdx.x & 7) * (gridDim.x >> 3) + (blockIdx.x >> 3);
    const int m0 = bx * 64;
    const int j0 = blockIdx.y * 64;
    const int ri = threadIdx.x >> 4, ci = threadIdx.x & 15;
    double acc[4][4];
#pragma unroll
    for (int u = 0; u < 4; ++u)
#pragma unroll
        for (int v = 0; v < 4; ++v) acc[u][v] = 0.0;

    for (int k0 = 0; k0 < 128; k0 += 32) {
        __syncthreads();
        for (int e = threadIdx.x; e < 64 * 16; e += 256) {
            int r = e >> 4, c2 = (e & 15) * 2;
            *(double2*)&As[r][c2] = *(const double2*)(A + (size_t)(m0 + r) * 128 + k0 + c2);
            int jw = j0 + r;
            float2 wv = (jw < 128) ? *(const float2*)(W + jw * 256 + k0 + c2)
                                   : *(const float2*)(W + (jw - 128) * 256 + 128 + k0 + c2);
            double2 wd; wd.x = (double)wv.x; wd.y = (double)wv.y;
            *(double2*)&Ws[r][c2] = wd;
        }
        __syncthreads();
        for (int c = 0; c < 32; c += 2) {
            double a0[4], a1[4], w0[4], w1[4];
#pragma unroll
            for (int u = 0; u < 4; ++u) { a0[u] = As[ri + 16 * u][c]; a1[u] = As[ri + 16 * u][c + 1]; }
#pragma unroll
            for (int v = 0; v < 4; ++v) { w0[v] = Ws[ci + 16 * v][c]; w1[v] = Ws[ci + 16 * v][c + 1]; }
#pragma unroll
            for (int u = 0; u < 4; ++u)
#pragma unroll
                for (int v = 0; v < 4; ++v)
                    acc[u][v] = fma(a1[u], w1[v], fma(a0[u], w0[v], acc[u][v]));
        }
    }
#pragma unroll
    for (int u = 0; u < 4; ++u) {
        int row = m0 + ri + 16 * u;
#pragma unroll
        for (int v = 0; v < 4; ++v)
            out[(size_t)row * 256 + j0 + ci + 16 * v] = acc[u][v];
    }
}

// ---------------- f64 GEMM small-tile (FFN modes): BM=32 x BN=64 x BK=32,
// 25.5 KB LDS, grid (1024,2) = 2048 blocks -> ~6 blocks/CU for latency hiding.
// MODE 1: gelu affine -> out; MODE 2: affine -> out (+ f32 copy to out32).
template<int MODE>
__global__ __launch_bounds__(256, 6) void gemm64s_kernel(
    const double* __restrict__ A, const float* __restrict__ W,
    const float* __restrict__ bias, const float* __restrict__ gamma,
    const float* __restrict__ beta, double* __restrict__ out,
    float* __restrict__ out32)
{
    __shared__ double As[32][34];
    __shared__ double Ws[64][34];
    const int bx = (blockIdx.x & 7) * (gridDim.x >> 3) + (blockIdx.x >> 3);
    const int m0 = bx * 32;
    const int j0 = blockIdx.y * 64;
    const int ri = threadIdx.x >> 4, ci = threadIdx.x & 15;
    double acc[2][4];
#pragma unroll
    for (int u = 0; u < 2; ++u)
#pragma unroll
        for (int v = 0; v < 4; ++v) acc[u][v] = 0.0;

    for (int k0 = 0; k0 < 128; k0 += 32) {
        __syncthreads();
        for (int e = threadIdx.x; e < 32 * 16; e += 256) {
            int r = e >> 4, c2 = (e & 15) * 2;
            *(double2*)&As[r][c2] = *(const double2*)(A + (size_t)(m0 + r) * 128 + k0 + c2);
        }
        for (int e = threadIdx.x; e < 64 * 16; e += 256) {
            int r = e >> 4, c2 = (e & 15) * 2;
            float2 wv = *(const float2*)(W + (j0 + r) * 128 + k0 + c2);
            double2 wd; wd.x = (double)wv.x; wd.y = (double)wv.y;
            *(double2*)&Ws[r][c2] = wd;
        }
        __syncthreads();
        for (int c = 0; c < 32; c += 2) {
            double a0[2], a1[2], w0[4], w1[4];
#pragma unroll
            for (int u = 0; u < 2; ++u) { a0[u] = As[ri + 16 * u][c]; a1[u] = As[ri + 16 * u][c + 1]; }
#pragma unroll
            for (int v = 0; v < 4; ++v) { w0[v] = Ws[ci + 16 * v][c]; w1[v] = Ws[ci + 16 * v][c + 1]; }
#pragma unroll
            for (int u = 0; u < 2; ++u)
#pragma unroll
                for (int v = 0; v < 4; ++v)
                    acc[u][v] = fma(a1[u], w1[v], fma(a0[u], w0[v], acc[u][v]));
        }
    }
#pragma unroll
    for (int u = 0; u < 2; ++u) {
        int row = m0 + ri + 16 * u;
#pragma unroll
        for (int v = 0; v < 4; ++v) {
            int jg = j0 + ci + 16 * v;
            double z = (acc[u][v] + (double)bias[jg]) * (double)gamma[jg] + (double)beta[jg];
            if (MODE == 1) {
                out[(size_t)row * 128 + jg] = gelu64(z);
            } else {
                out[(size_t)row * 128 + jg] = z;
                out32[(size_t)row * 128 + jg] = (float)z;
            }
        }
    }
}

// ---------------- combine64 v2 (in-place residual), XCD-chunked, 2-endpoint gelu.
__global__ __launch_bounds__(256) void combine64_kernel(
    double* __restrict__ xt, const double* __restrict__ G,
    const int* __restrict__ idx, const float* __restrict__ bias,
    const float* __restrict__ gamma, const float* __restrict__ beta)
{
    const int wb = (blockIdx.x & 7) * 2048 + (blockIdx.x >> 3);
    const int row = wb * 2 + (threadIdx.x >> 7);
    const int o = threadIdx.x & 127;
    const int b = row >> 11;
    const double* Gb = G + (size_t)(b * 2048) * 256;
    const int* id9 = idx + (size_t)row * 9;
    double g1  = G[(size_t)row * 256 + o];
    double g2i = G[(size_t)row * 256 + 128 + o];
    double base = g1 + (double)bias[o] - g2i;
    double gm = (double)gamma[o], bt = (double)beta[o];
    double g2mx = -1.0e300, g2mn = 1.0e300;
#pragma unroll
    for (int k = 0; k < 9; ++k) {
        int jn = id9[k];
        double g2 = Gb[(size_t)jn * 256 + 128 + o];
        g2mx = fmax(g2mx, g2);
        g2mn = fmin(g2mn, g2);
    }
    double z1 = (base + g2mx) * gm + bt;
    double z2 = (base + g2mn) * gm + bt;
    double mx = fmax(gelu64(z1), gelu64(z2));
    xt[(size_t)row * 128 + o] += mx;
}

// ---------------- f32 GEMM v3 (block-2 value path): BM=64/BN=128/BK=32,
// 27.6 KB LDS, float4 staging, acc[4][8], template MODE, XCD-chunked.
template<int MODE>
__global__ __launch_bounds__(256, 4) void gemm32f_kernel(
    const float* __restrict__ A, const float* __restrict__ W,
    const float* __restrict__ bias, const float* __restrict__ gamma,
    const float* __restrict__ beta, float* __restrict__ out)
{
    __shared__ float As[64][36];
    __shared__ float Ws[128][36];
    const int bx = (blockIdx.x & 7) * (gridDim.x >> 3) + (blockIdx.x >> 3);
    const int m0 = bx * 64;
    const int j0 = blockIdx.y * 128;
    const int ri = threadIdx.x >> 4, ci = threadIdx.x & 15;
    float acc[4][8];
#pragma unroll
    for (int u = 0; u < 4; ++u)
#pragma unroll
        for (int v = 0; v < 8; ++v) acc[u][v] = 0.0f;

    for (int k0 = 0; k0 < 128; k0 += 32) {
        __syncthreads();
        for (int e = threadIdx.x; e < 64 * 8; e += 256) {
            int r = e >> 3, q = (e & 7) * 4;
            *(float4*)&As[r][q] = *(const float4*)(A + (size_t)(m0 + r) * 128 + k0 + q);
        }
        for (int e = threadIdx.x; e < 128 * 8; e += 256) {
            int r = e >> 3, q = (e & 7) * 4;
            const float* src;
            if (MODE == 0) {
                int jw = j0 + r;
                src = (jw < 128) ? (W + jw * 256 + k0 + q) : (W + (jw - 128) * 256 + 128 + k0 + q);
            } else {
                src = W + r * 128 + k0 + q;
            }
            *(float4*)&Ws[r][q] = *(const float4*)src;
        }
        __syncthreads();
        for (int c = 0; c < 32; c += 4) {
            float4 a4[4];
#pragma unroll
            for (int u = 0; u < 4; ++u) a4[u] = *(const float4*)&As[ri + 16 * u][c];
#pragma unroll
            for (int v = 0; v < 8; ++v) {
                float4 w4 = *(const float4*)&Ws[ci + 16 * v][c];
#pragma unroll
                for (int u = 0; u < 4; ++u) {
                    acc[u][v] = fmaf(a4[u].x, w4.x, fmaf(a4[u].y, w4.y,
                                fmaf(a4[u].z, w4.z, fmaf(a4[u].w, w4.w, acc[u][v]))));
                }
            }
        }
    }
#pragma unroll
    for (int u = 0; u < 4; ++u) {
        int row = m0 + ri + 16 * u;
#pragma unroll
        for (int v = 0; v < 8; ++v) {
            int jn = ci + 16 * v;
            float val = acc[u][v];
            if (MODE == 0) {
                out[(size_t)row * 256 + j0 + jn] = val;
            } else if (MODE == 1) {
                float z = (val + bias[jn]) * gamma[jn] + beta[jn];
                out[(size_t)row * 128 + jn] = gelu_exact(z);
            } else {
                float z = (val + bias[jn]) * gamma[jn] + beta[jn];
                out[(size_t)row * 128 + jn] = z;
            }
        }
    }
}

// ---------------- combine f32 v2 (block 2; in-place safe), XCD-chunked, 2-endpoint gelu
__global__ __launch_bounds__(256) void combine_kernel(
    const float* __restrict__ xt, const float* __restrict__ G,
    const int* __restrict__ idx, const float* __restrict__ bias,
    const float* __restrict__ gamma, const float* __restrict__ beta,
    float* __restrict__ xt2)
{
    const int wb = (blockIdx.x & 7) * 2048 + (blockIdx.x >> 3);
    const int row = wb * 2 + (threadIdx.x >> 7);
    const int o = threadIdx.x & 127;
    const int b = row >> 11;
    const float* Gb = G + (size_t)(b * 2048) * 256;
    const int* id9 = idx + (size_t)row * 9;
    float g1  = G[(size_t)row * 256 + o];
    float g2i = G[(size_t)row * 256 + 128 + o];
    float base = g1 + bias[o] - g2i;
    float gm = gamma[o], bt = beta[o];
    float g2mx = -3.4e38f, g2mn = 3.4e38f;
#pragma unroll
    for (int k = 0; k < 9; ++k) {
        int jn = id9[k];
        float g2 = Gb[(size_t)jn * 256 + 128 + o];
        g2mx = fmaxf(g2mx, g2);
        g2mn = fminf(g2mn, g2);
    }
    float z1 = (base + g2mx) * gm + bt;
    float z2 = (base + g2mn) * gm + bt;
    float mx = fmaxf(gelu_exact(z1), gelu_exact(z2));
    xt2[(size_t)row * 128 + o] = xt[(size_t)row * 128 + o] + mx;
}

extern "C" void kernel_launch(void* const* d_in, const int* in_sizes, int n_in,
                              void* d_out, int out_size, void* d_ws, size_t ws_size,
                              hipStream_t stream)
{
    const float* ts       = (const float*)d_in[0];
    const float* conv1_w  = (const float*)d_in[1];
    const float* conv1_b  = (const float*)d_in[2];
    const float* conv2_w  = (const float*)d_in[3];
    const float* conv2_b  = (const float*)d_in[4];
    const float* gconv_w  = (const float*)d_in[5];
    const float* gconv_b  = (const float*)d_in[6];
    const float* gconv_g  = (const float*)d_in[7];
    const float* gconv_be = (const float*)d_in[8];
    const float* ffn1_w   = (const float*)d_in[9];
    const float* ffn1_b   = (const float*)d_in[10];
    const float* ffn1_g   = (const float*)d_in[11];
    const float* ffn1_be  = (const float*)d_in[12];
    const float* ffn2_w   = (const float*)d_in[13];
    const float* ffn2_b   = (const float*)d_in[14];
    const float* ffn2_g   = (const float*)d_in[15];
    const float* ffn2_be  = (const float*)d_in[16];
    (void)in_sizes; (void)n_in; (void)out_size; (void)ws_size;

    // ---- workspace layout (byte offsets), lifetime-overlaid; peak ~101.8 MB ----
    char* base = (char*)d_ws;
    double*         XT64   = (double*)(base + 0);            // 33.55 MB
    double*         H1_64  = (double*)(base + 33554432);     // 16.78 MB (conv phase only)
    unsigned short* XH     = (unsigned short*)(base + 33554432); // 8.39 MB (norm -> knn)
    unsigned short* XM     = (unsigned short*)(base + 41943040); // 8.39 MB (norm -> knn)
    int*            CAND   = (int*)   (base + 50331648);     // 4.19 MB  (knn -> rescore; 32/row)
    double*         XN64_1 = (double*)(base + 54525952);     // 33.55 MB (blk1 norm -> rescore; dies before G64 use)
    double*         SQ64_1 = (double*)(base + 88080384);     // 0.26 MB
    double*         G64    = (double*)(base + 33554432);     // 67.11 MB (gemm0 -> combine, blk1)
    double*         H64    = (double*)(base + 33554432);     // 33.55 MB (ffn1 -> ffn2, blk1)
    float*          XT32P  = (float*) (base + 67108864);     // 16.78 MB (blk1 ffn2 -> blk2 value path)
    int*            IDX    = (int*)   (base + 100663296);    // 1.18 MB  (rescore -> combine)
    float*          G32    = (float*) (base + 33554432);     // 33.55 MB (blk2)
    float*          H32    = (float*) (base + 33554432);     // 16.78 MB (blk2 ffn)
    double*         XN64_2 = XT64;                           // blk2: in-place over XT64 (dead after blk2 norm)
    double*         SQ64_2 = SQ64_1;

    float* fout = (float*)d_out;

    conv1_kernel64<<<dim3(64, 16), 256, 0, stream>>>(ts, conv1_w, conv1_b, H1_64);
    conv2_kernel64<<<dim3(64, 16), 256, 0, stream>>>(H1_64, conv2_w, conv2_b, XT64);

    // ---------- block 1 (f64 value path; indices exact) ----------
    norm_planes_kernel<<<8192, 256, 0, stream>>>(XT64, XH, XM, XN64_1, SQ64_1);
    knn_mfma11_kernel<<<1024, 256, 0, stream>>>(XH, XM, CAND);
    rescore5_kernel<<<8192, 256, 0, stream>>>(XN64_1, SQ64_1, CAND, IDX);
    gemm64t0_kernel<<<dim3(512, 4), 256, 0, stream>>>(XT64, gconv_w, G64);
    combine64_kernel<<<16384, 256, 0, stream>>>(
        XT64, G64, IDX, gconv_b, gconv_g, gconv_be);
    gemm64s_kernel<1><<<dim3(1024, 2), 256, 0, stream>>>(
        XT64, ffn1_w, ffn1_b, ffn1_g, ffn1_be, H64, nullptr);
    gemm64s_kernel<2><<<dim3(1024, 2), 256, 0, stream>>>(
        H64, ffn2_w, ffn2_b, ffn2_g, ffn2_be, XT64, XT32P);

    // ---------- block 2 (indices exact via f64; value path f32) ----------
    norm_planes_kernel<<<8192, 256, 0, stream>>>(XT64, XH, XM, XN64_2, SQ64_2);
    knn_mfma11_kernel<<<1024, 256, 0, stream>>>(XH, XM, CAND);
    rescore5_kernel<<<8192, 256, 0, stream>>>(XN64_2, SQ64_2, CAND, IDX);
    gemm32f_kernel<0><<<dim3(512, 2), 256, 0, stream>>>(
        XT32P, gconv_w + 32768, nullptr, nullptr, nullptr, G32);
    combine_kernel<<<16384, 256, 0, stream>>>(
        XT32P, G32, IDX, gconv_b + 128, gconv_g + 128, gconv_be + 128, XT32P);
    gemm32f_kernel<1><<<dim3(512, 1), 256, 0, stream>>>(
        XT32P, ffn1_w + 16384, ffn1_b + 128, ffn1_g + 128, ffn1_be + 128, H32);
    gemm32f_kernel<2><<<dim3(512, 1), 256, 0, stream>>>(
        H32, ffn2_w + 16384, ffn2_b + 128, ffn2_g + 128, ffn2_be + 128, fout);
}

// Round 21
// 635.134 us; speedup vs baseline: 1.0146x; 1.0146x over previous
//
#include <hip/hip_runtime.h>
#include <hip/hip_bf16.h>

#define DEV_INLINE __device__ __forceinline__

typedef short s16x8 __attribute__((ext_vector_type(8)));
typedef float f32x4 __attribute__((ext_vector_type(4)));

DEV_INLINE float gelu_exact(float x) {
    return 0.5f * x * (1.0f + erff(x * 0.70710678118654752440f));
}
DEV_INLINE double gelu64(double x) {
    return 0.5 * x * (1.0 + erf(x * 0.70710678118654752440));
}
DEV_INLINE unsigned short f2bf_rne(float f) {
    unsigned u = __float_as_uint(f);
    unsigned r = u + 0x7FFFu + ((u >> 16) & 1u);
    return (unsigned short)(r >> 16);
}
DEV_INLINE float bf2f(unsigned short h) { return __uint_as_float(((unsigned)h) << 16); }

DEV_INLINE void gload_lds16(const void* g, void* l) {
    __builtin_amdgcn_global_load_lds(
        (const __attribute__((address_space(1))) unsigned int*)g,
        (__attribute__((address_space(3))) unsigned int*)l, 16, 0, 0);
}

DEV_INLINE unsigned med3u32(unsigned a, unsigned b, unsigned c) {
    unsigned d;
    asm("v_med3_u32 %0, %1, %2, %3" : "=v"(d) : "v"(a), "v"(b), "v"(c));
    return d;
}

// ---------------- conv1 (f64): ts (16,100,2048) f32 -> relu(causal conv d=1) -> h1 (16,64,2048) f64
__global__ __launch_bounds__(256) void conv1_kernel64(
    const float* __restrict__ x, const float* __restrict__ w,
    const float* __restrict__ bias, double* __restrict__ y)
{
    const int b = blockIdx.y;
    const int t0 = blockIdx.x * 32;
    __shared__ double xs[100][34];
    for (int e = threadIdx.x; e < 100 * 34; e += 256) {
        int i = e / 34, u = e - i * 34;
        int t = t0 - 2 + u;
        xs[i][u] = (t >= 0) ? (double)x[(b * 100 + i) * 2048 + t] : 0.0;
    }
    __syncthreads();
    const int o = threadIdx.x & 63;
    const int ts = (threadIdx.x >> 6) * 8;
    double acc[8];
    double bv = (double)bias[o];
#pragma unroll
    for (int j = 0; j < 8; ++j) acc[j] = bv;
    const float* wo = w + o * 300;
    for (int i = 0; i < 100; ++i) {
        double w0 = (double)wo[i * 3 + 0], w1 = (double)wo[i * 3 + 1], w2 = (double)wo[i * 3 + 2];
#pragma unroll
        for (int j = 0; j < 8; ++j) {
            acc[j] = fma(w0, xs[i][ts + j],
                     fma(w1, xs[i][ts + j + 1],
                     fma(w2, xs[i][ts + j + 2], acc[j])));
        }
    }
#pragma unroll
    for (int j = 0; j < 8; ++j)
        y[(b * 64 + o) * 2048 + t0 + ts + j] = fmax(acc[j], 0.0);
}

// ---------------- conv2 (f64): h1 -> relu(causal conv d=2) -> xt64 (16,2048,128) transposed
__global__ __launch_bounds__(256) void conv2_kernel64(
    const double* __restrict__ x, const float* __restrict__ w,
    const float* __restrict__ bias, double* __restrict__ xt)
{
    const int b = blockIdx.y;
    const int t0 = blockIdx.x * 32;
    __shared__ double xs[64][36];
    for (int e = threadIdx.x; e < 64 * 36; e += 256) {
        int i = e / 36, u = e - i * 36;
        int t = t0 - 4 + u;
        xs[i][u] = (t >= 0) ? x[(b * 64 + i) * 2048 + t] : 0.0;
    }
    __syncthreads();
    const int o = threadIdx.x & 127;
    const int ts = (threadIdx.x >> 7) * 16;
    double acc[16];
    double bv = (double)bias[o];
#pragma unroll
    for (int j = 0; j < 16; ++j) acc[j] = bv;
    const float* wo = w + o * 192;
    for (int i = 0; i < 64; ++i) {
        double w0 = (double)wo[i * 3 + 0], w1 = (double)wo[i * 3 + 1], w2 = (double)wo[i * 3 + 2];
#pragma unroll
        for (int j = 0; j < 16; ++j) {
            acc[j] = fma(w0, xs[i][ts + j],
                     fma(w1, xs[i][ts + j + 2],
                     fma(w2, xs[i][ts + j + 4], acc[j])));
        }
    }
#pragma unroll
    for (int j = 0; j < 16; ++j)
        xt[(size_t)(b * 2048 + t0 + ts + j) * 128 + o] = fmax(acc[j], 0.0);
}

// ---------------- norm+split: xt64 -> f64-normalized rows (XN64, SQ64) + hi/mid bf16 planes
// NOTE: XN64 may alias xt64 (in-place): each element is read only by the thread that writes it.
__global__ __launch_bounds__(256) void norm_planes_kernel(
    const double* __restrict__ xt64, unsigned short* __restrict__ XH,
    unsigned short* __restrict__ XM, double* __restrict__ XN64,
    double* __restrict__ SQ64)
{
    const int row = blockIdx.x * 4 + (threadIdx.x >> 6);
    const int lane = threadIdx.x & 63;
    double v0 = xt64[(size_t)row * 128 + lane * 2];
    double v1 = xt64[(size_t)row * 128 + lane * 2 + 1];
    double s = v0 * v0 + v1 * v1;
#pragma unroll
    for (int off = 32; off > 0; off >>= 1) s += __shfl_xor(s, off);
    double inv = 1.0 / fmax(sqrt(s), 1e-12);
    double n0 = v0 * inv, n1 = v1 * inv;
    XN64[(size_t)row * 128 + lane * 2]     = n0;
    XN64[(size_t)row * 128 + lane * 2 + 1] = n1;
    double q = n0 * n0 + n1 * n1;
#pragma unroll
    for (int off = 32; off > 0; off >>= 1) q += __shfl_xor(q, off);
    if (lane == 0) SQ64[row] = q;
    float x0 = (float)n0, x1 = (float)n1;
    unsigned short h0 = f2bf_rne(x0), h1 = f2bf_rne(x1);
    unsigned short m0 = f2bf_rne(x0 - bf2f(h0)), m1 = f2bf_rne(x1 - bf2f(h1));
    ushort2 hv; hv.x = h0; hv.y = h1;
    ushort2 mv; mv.x = m0; mv.y = m1;
    *(ushort2*)(XH + (size_t)row * 128 + lane * 2) = hv;
    *(ushort2*)(XM + (size_t)row * 128 + lane * 2) = mv;
}

// sorted-insert via med3: for sorted k0>=...>=k8 and candidate c,
// k0' = max(k0,c); ki' = median(k_{i-1}, k_i, c). 9 independent ops.
#define INS9(cc) do { \
    unsigned c_ = (cc); \
    unsigned n0_ = (k0 > c_) ? k0 : c_; \
    unsigned n1_ = med3u32(k0, k1, c_); \
    unsigned n2_ = med3u32(k1, k2, c_); \
    unsigned n3_ = med3u32(k2, k3, c_); \
    unsigned n4_ = med3u32(k3, k4, c_); \
    unsigned n5_ = med3u32(k4, k5, c_); \
    unsigned n6_ = med3u32(k5, k6, c_); \
    unsigned n7_ = med3u32(k6, k7, c_); \
    unsigned n8_ = med3u32(k7, k8, c_); \
    k0 = n0_; k1 = n1_; k2 = n2_; k3 = n3_; k4 = n4_; \
    k5 = n5_; k6 = n6_; k7 = n7_; k8 = n8_; \
} while (0)

// ---------------- knn stage 1 v12: v10 structure (512 blocks x 512 thr, 32-row
// tiles, dbuf 32KB) with FULL 16-slot XOR swizzle (r&15): the ct-group's 16 rows
// now map bijectively onto all 16 16B slots -> uniform 8 bank-accesses/bank
// (the wave64 floor), eliminating the structural 2-way slot collision of r&7.
__global__ __launch_bounds__(512, 4) void knn_mfma12_kernel(
    const unsigned short* __restrict__ XH, const unsigned short* __restrict__ XM,
    int* __restrict__ cand_out)
{
    __shared__ __align__(16) unsigned char smem[32768];  // 2 bufs x (H 8KB | M 8KB)

    const int tid = threadIdx.x, wave = tid >> 6, lane = tid & 63;
    const int bid = blockIdx.x;
    const int j = bid >> 3;                      // 0..63
    const int b = (bid & 7) * 2 + (j >> 5);      // XCD-local batch
    const int ntile = (j & 31) >> 1;             // 0..15
    const int mhalf = j & 1;                     // 0..1
    const int n0 = ntile * 128;
    const int mstart = mhalf * 1024;
    const unsigned short* Hb = XH + (size_t)b * 2048 * 128;
    const unsigned short* Mb = XM + (size_t)b * 2048 * 128;

    s16x8 aH[4], aM[4];
    {
        int arow = n0 + wave * 16 + (lane & 15);
        const unsigned short* hrow = Hb + (size_t)arow * 128;
        const unsigned short* mrow = Mb + (size_t)arow * 128;
        int cb = (lane >> 4) * 8;
#pragma unroll
        for (int s = 0; s < 4; ++s) {
            aH[s] = *(const s16x8*)(hrow + s * 32 + cb);
            aM[s] = *(const s16x8*)(mrow + s * 32 + cb);
        }
    }

    // staging: 32-row tiles; c in {0,1}: r = (wave&3)*8 + c*4 + (lane>>4);
    // inverse-swizzled source col (full 16-slot involution); linear LDS dest.
    const unsigned short* Pb = (wave >> 2) ? Mb : Hb;
    const unsigned short* gsrc0; const unsigned short* gsrc1;
    {
        int r0 = (wave & 3) * 8 + 0 + (lane >> 4), c0 = (lane & 15) ^ (r0 & 15);
        int r1 = (wave & 3) * 8 + 4 + (lane >> 4), c1 = (lane & 15) ^ (r1 & 15);
        gsrc0 = Pb + (size_t)(mstart + r0) * 128 + c0 * 8;
        gsrc1 = Pb + (size_t)(mstart + r1) * 128 + c1 * 8;
    }
    const unsigned ldsbase = (wave >> 2) * 8192 + (wave & 3) * 2048;

    unsigned k0 = 0, k1 = 0, k2 = 0, k3 = 0, k4 = 0, k5 = 0, k6 = 0, k7 = 0, k8 = 0;

    gload_lds16(gsrc0, smem + ldsbase);
    gload_lds16(gsrc1, smem + ldsbase + 1024);
    __syncthreads();

    int cur = 0;
    for (int t = 0; t < 32; ++t) {
        if (t < 31) {
            size_t go = (size_t)(t + 1) * 32 * 128;
            unsigned lb = (cur ^ 1) * 16384 + ldsbase;
            gload_lds16(gsrc0 + go, smem + lb);
            gload_lds16(gsrc1 + go, smem + lb + 1024);
        }
        const unsigned char* B0 = smem + cur * 16384;
        const unsigned char* B1 = B0 + 8192;
#pragma unroll
        for (int ct = 0; ct < 2; ++ct) {
            f32x4 accA; accA[0] = 0.f; accA[1] = 0.f; accA[2] = 0.f; accA[3] = 0.f;
            f32x4 accB; accB[0] = 0.f; accB[1] = 0.f; accB[2] = 0.f; accB[3] = 0.f;
            int r = ct * 16 + (lane & 15);
#pragma unroll
            for (int s = 0; s < 4; ++s) {
                int off = r * 256 + (((s * 64) + ((lane >> 4) * 16)) ^ ((r & 15) << 4));
                s16x8 bH = *(const s16x8*)(B0 + off);
                s16x8 bM = *(const s16x8*)(B1 + off);
                accA = __builtin_amdgcn_mfma_f32_16x16x32_bf16(bH, aH[s], accA, 0, 0, 0);
                accB = __builtin_amdgcn_mfma_f32_16x16x32_bf16(bM, aH[s], accB, 0, 0, 0);
                accB = __builtin_amdgcn_mfma_f32_16x16x32_bf16(bH, aM[s], accB, 0, 0, 0);
            }
            // within-lane candidate id = t*8 + ct*4 + reg (256 total, ascending m)
            const unsigned Lb = (unsigned)(255 - (t * 8 + ct * 4));
            unsigned key0 = (__float_as_uint(accA[0] + accB[0] + 2.0f) & 0xFFFFFF00u) | (Lb - 0u);
            unsigned key1 = (__float_as_uint(accA[1] + accB[1] + 2.0f) & 0xFFFFFF00u) | (Lb - 1u);
            unsigned key2 = (__float_as_uint(accA[2] + accB[2] + 2.0f) & 0xFFFFFF00u) | (Lb - 2u);
            unsigned key3 = (__float_as_uint(accA[3] + accB[3] + 2.0f) & 0xFFFFFF00u) | (Lb - 3u);
            INS9(key0);
            INS9(key1);
            INS9(key2);
            INS9(key3);
        }
        __syncthreads();
        cur ^= 1;
    }

    const int g = lane >> 4;
    const int row = b * 2048 + n0 + wave * 16 + (lane & 15);
#pragma unroll
    for (int pass = 0; pass < 16; ++pass) {
        unsigned mykey = k0;
        int L = 255 - (int)(mykey & 0xFFu);
        int mym = mstart + (L >> 3) * 32 + ((L >> 2) & 1) * 16 + g * 4 + (L & 3);
        unsigned bkey = mykey; int bm = mym;
        unsigned ok = (unsigned)__shfl_xor((int)bkey, 16); int om = __shfl_xor(bm, 16);
        bool tk = (ok > bkey) || (ok == bkey && om < bm);
        bkey = tk ? ok : bkey; bm = tk ? om : bm;
        ok = (unsigned)__shfl_xor((int)bkey, 32); om = __shfl_xor(bm, 32);
        tk = (ok > bkey) || (ok == bkey && om < bm);
        bkey = tk ? ok : bkey; bm = tk ? om : bm;
        if (mym == bm) {
            k0 = k1; k1 = k2; k2 = k3; k3 = k4; k4 = k5; k5 = k6; k6 = k7; k7 = k8; k8 = 0;
        }
        if (g == (pass & 3)) cand_out[(size_t)row * 32 + mhalf * 16 + pass] = bm;
    }
}

// ---------------- knn stage 2 v5 (f64): coalesced rescore + rank-by-count selection.
// (256,4): VGPR cap 128; ~60 live regs, NO spill (round-18 lesson).
__global__ __launch_bounds__(256, 4) void rescore5_kernel(
    const double* __restrict__ XN64, const double* __restrict__ SQ64,
    const int* __restrict__ cand, int* __restrict__ idx_out)
{
    const int wid = threadIdx.x >> 6, lane = threadIdx.x & 63;
    const int wb = (blockIdx.x & 7) * 1024 + (blockIdx.x >> 3);  // 8192 blocks, bijective
    const int n = wb * 4 + wid;
    const int b = n >> 11;
    const int g = lane >> 4, e = lane & 15;
    const double* Xb = XN64 + (size_t)(b * 2048) * 128;
    const double* SQb = SQ64 + (size_t)b * 2048;

    double2 xq[4];
    const double* xqp = XN64 + (size_t)n * 128;
#pragma unroll
    for (int it = 0; it < 4; ++it)
        xq[it] = *(const double2*)(xqp + it * 32 + e * 2);

    int mi[8];
    double s[8];
#pragma unroll
    for (int bb = 0; bb < 8; ++bb) {
        int m = cand[(size_t)n * 32 + bb * 4 + g];
        mi[bb] = m;
        const double* xm = Xb + (size_t)m * 128;
        double a0 = 0.0, a1 = 0.0;
#pragma unroll
        for (int it = 0; it < 4; ++it) {
            double2 v = *(const double2*)(xm + it * 32 + e * 2);
            a0 = fma(xq[it].x, v.x, a0);
            a1 = fma(xq[it].y, v.y, a1);
        }
        s[bb] = a0 + a1;
    }
#pragma unroll
    for (int bb = 0; bb < 8; ++bb) {
        double d = s[bb];
        d += __shfl_xor(d, 1);
        d += __shfl_xor(d, 2);
        d += __shfl_xor(d, 4);
        d += __shfl_xor(d, 8);
        s[bb] = 2.0 * d - SQb[mi[bb]];
    }
    double mys = s[0]; int mym = mi[0];
#pragma unroll
    for (int q = 1; q < 8; ++q) {
        bool p = (e == q);
        mys = p ? s[q] : mys;
        mym = p ? mi[q] : mym;
    }
    int cnt = 0;
#pragma unroll
    for (int bb = 0; bb < 8; ++bb) {
        cnt += ((s[bb] > mys) || (s[bb] == mys && mi[bb] < mym)) ? 1 : 0;
        double a16 = __shfl_xor(s[bb], 16); int m16 = __shfl_xor(mi[bb], 16);
        cnt += ((a16 > mys) || (a16 == mys && m16 < mym)) ? 1 : 0;
        double a32 = __shfl_xor(s[bb], 32); int m32 = __shfl_xor(mi[bb], 32);
        cnt += ((a32 > mys) || (a32 == mys && m32 < mym)) ? 1 : 0;
        double a48 = __shfl_xor(a16, 32);  int m48 = __shfl_xor(m16, 32);
        cnt += ((a48 > mys) || (a48 == mys && m48 < mym)) ? 1 : 0;
    }
    if (e < 8 && cnt < 9)
        idx_out[(size_t)n * 9 + cnt] = mym;
}

// ---------------- f64 GEMM v2 (K=128 in 4 chunks of 32 -> 34.8 KB LDS, 4 blocks/CU,
// vectorized double2/float2 staging, template MODE). Bit-identical FMA order to v1.
template<int MODE>
__global__ __launch_bounds__(256, 4) void gemm64t_kernel(
    const double* __restrict__ A, const float* __restrict__ W,
    const float* __restrict__ bias, const float* __restrict__ gamma,
    const float* __restrict__ beta, double* __restrict__ out,
    float* __restrict__ out32)
{
    __shared__ double As[64][34];
    __shared__ double Ws[64][34];
    const int bx = (blockIdx.x & 7) * (gridDim.x >> 3) + (blockIdx.x >> 3);
    const int m0 = bx * 64;
    const int j0 = blockIdx.y * 64;
    const int ri = threadIdx.x >> 4, ci = threadIdx.x & 15;
    double acc[4][4];
#pragma unroll
    for (int u = 0; u < 4; ++u)
#pragma unroll
        for (int v = 0; v < 4; ++v) acc[u][v] = 0.0;

    for (int k0 = 0; k0 < 128; k0 += 32) {
        __syncthreads();
        for (int e = threadIdx.x; e < 64 * 16; e += 256) {
            int r = e >> 4, c2 = (e & 15) * 2;
            *(double2*)&As[r][c2] = *(const double2*)(A + (size_t)(m0 + r) * 128 + k0 + c2);
            int jw = j0 + r;
            float2 wv;
            if (MODE == 0) {
                wv = (jw < 128) ? *(const float2*)(W + jw * 256 + k0 + c2)
                                : *(const float2*)(W + (jw - 128) * 256 + 128 + k0 + c2);
            } else {
                wv = *(const float2*)(W + jw * 128 + k0 + c2);
            }
            double2 wd; wd.x = (double)wv.x; wd.y = (double)wv.y;
            *(double2*)&Ws[r][c2] = wd;
        }
        __syncthreads();
        for (int c = 0; c < 32; c += 2) {
            double a0[4], a1[4], w0[4], w1[4];
#pragma unroll
            for (int u = 0; u < 4; ++u) { a0[u] = As[ri + 16 * u][c]; a1[u] = As[ri + 16 * u][c + 1]; }
#pragma unroll
            for (int v = 0; v < 4; ++v) { w0[v] = Ws[ci + 16 * v][c]; w1[v] = Ws[ci + 16 * v][c + 1]; }
#pragma unroll
            for (int u = 0; u < 4; ++u)
#pragma unroll
                for (int v = 0; v < 4; ++v)
                    acc[u][v] = fma(a1[u], w1[v], fma(a0[u], w0[v], acc[u][v]));
        }
    }
#pragma unroll
    for (int u = 0; u < 4; ++u) {
        int row = m0 + ri + 16 * u;
#pragma unroll
        for (int v = 0; v < 4; ++v) {
            int jl = ci + 16 * v;
            double val = acc[u][v];
            if (MODE == 0) {
                out[(size_t)row * 256 + j0 + jl] = val;
            } else {
                int jg = j0 + jl;
                double z = (val + (double)bias[jg]) * (double)gamma[jg] + (double)beta[jg];
                if (MODE == 1) {
                    out[(size_t)row * 128 + jg] = gelu64(z);
                } else {
                    out[(size_t)row * 128 + jg] = z;
                    out32[(size_t)row * 128 + jg] = (float)z;
                }
            }
        }
    }
}

// ---------------- combine64 v2 (in-place residual), XCD-chunked, 2-endpoint gelu.
__global__ __launch_bounds__(256) void combine64_kernel(
    double* __restrict__ xt, const double* __restrict__ G,
    const int* __restrict__ idx, const float* __restrict__ bias,
    const float* __restrict__ gamma, const float* __restrict__ beta)
{
    const int wb = (blockIdx.x & 7) * 2048 + (blockIdx.x >> 3);
    const int row = wb * 2 + (threadIdx.x >> 7);
    const int o = threadIdx.x & 127;
    const int b = row >> 11;
    const double* Gb = G + (size_t)(b * 2048) * 256;
    const int* id9 = idx + (size_t)row * 9;
    double g1  = G[(size_t)row * 256 + o];
    double g2i = G[(size_t)row * 256 + 128 + o];
    double base = g1 + (double)bias[o] - g2i;
    double gm = (double)gamma[o], bt = (double)beta[o];
    double g2mx = -1.0e300, g2mn = 1.0e300;
#pragma unroll
    for (int k = 0; k < 9; ++k) {
        int jn = id9[k];
        double g2 = Gb[(size_t)jn * 256 + 128 + o];
        g2mx = fmax(g2mx, g2);
        g2mn = fmin(g2mn, g2);
    }
    double z1 = (base + g2mx) * gm + bt;
    double z2 = (base + g2mn) * gm + bt;
    double mx = fmax(gelu64(z1), gelu64(z2));
    xt[(size_t)row * 128 + o] += mx;
}

// ---------------- f32 GEMM v3 (block-2 value path): BM=64/BN=128/BK=32,
// 27.6 KB LDS, float4 staging, acc[4][8], template MODE, XCD-chunked.
template<int MODE>
__global__ __launch_bounds__(256, 4) void gemm32f_kernel(
    const float* __restrict__ A, const float* __restrict__ W,
    const float* __restrict__ bias, const float* __restrict__ gamma,
    const float* __restrict__ beta, float* __restrict__ out)
{
    __shared__ float As[64][36];
    __shared__ float Ws[128][36];
    const int bx = (blockIdx.x & 7) * (gridDim.x >> 3) + (blockIdx.x >> 3);
    const int m0 = bx * 64;
    const int j0 = blockIdx.y * 128;
    const int ri = threadIdx.x >> 4, ci = threadIdx.x & 15;
    float acc[4][8];
#pragma unroll
    for (int u = 0; u < 4; ++u)
#pragma unroll
        for (int v = 0; v < 8; ++v) acc[u][v] = 0.0f;

    for (int k0 = 0; k0 < 128; k0 += 32) {
        __syncthreads();
        for (int e = threadIdx.x; e < 64 * 8; e += 256) {
            int r = e >> 3, q = (e & 7) * 4;
            *(float4*)&As[r][q] = *(const float4*)(A + (size_t)(m0 + r) * 128 + k0 + q);
        }
        for (int e = threadIdx.x; e < 128 * 8; e += 256) {
            int r = e >> 3, q = (e & 7) * 4;
            const float* src;
            if (MODE == 0) {
                int jw = j0 + r;
                src = (jw < 128) ? (W + jw * 256 + k0 + q) : (W + (jw - 128) * 256 + 128 + k0 + q);
            } else {
                src = W + r * 128 + k0 + q;
            }
            *(float4*)&Ws[r][q] = *(const float4*)src;
        }
        __syncthreads();
        for (int c = 0; c < 32; c += 4) {
            float4 a4[4];
#pragma unroll
            for (int u = 0; u < 4; ++u) a4[u] = *(const float4*)&As[ri + 16 * u][c];
#pragma unroll
            for (int v = 0; v < 8; ++v) {
                float4 w4 = *(const float4*)&Ws[ci + 16 * v][c];
#pragma unroll
                for (int u = 0; u < 4; ++u) {
                    acc[u][v] = fmaf(a4[u].x, w4.x, fmaf(a4[u].y, w4.y,
                                fmaf(a4[u].z, w4.z, fmaf(a4[u].w, w4.w, acc[u][v]))));
                }
            }
        }
    }
#pragma unroll
    for (int u = 0; u < 4; ++u) {
        int row = m0 + ri + 16 * u;
#pragma unroll
        for (int v = 0; v < 8; ++v) {
            int jn = ci + 16 * v;
            float val = acc[u][v];
            if (MODE == 0) {
                out[(size_t)row * 256 + j0 + jn] = val;
            } else if (MODE == 1) {
                float z = (val + bias[jn]) * gamma[jn] + beta[jn];
                out[(size_t)row * 128 + jn] = gelu_exact(z);
            } else {
                float z = (val + bias[jn]) * gamma[jn] + beta[jn];
                out[(size_t)row * 128 + jn] = z;
            }
        }
    }
}

// ---------------- combine f32 v2 (block 2; in-place safe), XCD-chunked, 2-endpoint gelu
__global__ __launch_bounds__(256) void combine_kernel(
    const float* __restrict__ xt, const float* __restrict__ G,
    const int* __restrict__ idx, const float* __restrict__ bias,
    const float* __restrict__ gamma, const float* __restrict__ beta,
    float* __restrict__ xt2)
{
    const int wb = (blockIdx.x & 7) * 2048 + (blockIdx.x >> 3);
    const int row = wb * 2 + (threadIdx.x >> 7);
    const int o = threadIdx.x & 127;
    const int b = row >> 11;
    const float* Gb = G + (size_t)(b * 2048) * 256;
    const int* id9 = idx + (size_t)row * 9;
    float g1  = G[(size_t)row * 256 + o];
    float g2i = G[(size_t)row * 256 + 128 + o];
    float base = g1 + bias[o] - g2i;
    float gm = gamma[o], bt = beta[o];
    float g2mx = -3.4e38f, g2mn = 3.4e38f;
#pragma unroll
    for (int k = 0; k < 9; ++k) {
        int jn = id9[k];
        float g2 = Gb[(size_t)jn * 256 + 128 + o];
        g2mx = fmaxf(g2mx, g2);
        g2mn = fminf(g2mn, g2);
    }
    float z1 = (base + g2mx) * gm + bt;
    float z2 = (base + g2mn) * gm + bt;
    float mx = fmaxf(gelu_exact(z1), gelu_exact(z2));
    xt2[(size_t)row * 128 + o] = xt[(size_t)row * 128 + o] + mx;
}

extern "C" void kernel_launch(void* const* d_in, const int* in_sizes, int n_in,
                              void* d_out, int out_size, void* d_ws, size_t ws_size,
                              hipStream_t stream)
{
    const float* ts       = (const float*)d_in[0];
    const float* conv1_w  = (const float*)d_in[1];
    const float* conv1_b  = (const float*)d_in[2];
    const float* conv2_w  = (const float*)d_in[3];
    const float* conv2_b  = (const float*)d_in[4];
    const float* gconv_w  = (const float*)d_in[5];
    const float* gconv_b  = (const float*)d_in[6];
    const float* gconv_g  = (const float*)d_in[7];
    const float* gconv_be = (const float*)d_in[8];
    const float* ffn1_w   = (const float*)d_in[9];
    const float* ffn1_b   = (const float*)d_in[10];
    const float* ffn1_g   = (const float*)d_in[11];
    const float* ffn1_be  = (const float*)d_in[12];
    const float* ffn2_w   = (const float*)d_in[13];
    const float* ffn2_b   = (const float*)d_in[14];
    const float* ffn2_g   = (const float*)d_in[15];
    const float* ffn2_be  = (const float*)d_in[16];
    (void)in_sizes; (void)n_in; (void)out_size; (void)ws_size;

    // ---- workspace layout (byte offsets), lifetime-overlaid; peak ~101.8 MB ----
    char* base = (char*)d_ws;
    double*         XT64   = (double*)(base + 0);            // 33.55 MB
    double*         H1_64  = (double*)(base + 33554432);     // 16.78 MB (conv phase only)
    unsigned short* XH     = (unsigned short*)(base + 33554432); // 8.39 MB (norm -> knn)
    unsigned short* XM     = (unsigned short*)(base + 41943040); // 8.39 MB (norm -> knn)
    int*            CAND   = (int*)   (base + 50331648);     // 4.19 MB  (knn -> rescore; 32/row)
    double*         XN64_1 = (double*)(base + 54525952);     // 33.55 MB (blk1 norm -> rescore; dies before G64 use)
    double*         SQ64_1 = (double*)(base + 88080384);     // 0.26 MB
    double*         G64    = (double*)(base + 33554432);     // 67.11 MB (gemm0 -> combine, blk1)
    double*         H64    = (double*)(base + 33554432);     // 33.55 MB (ffn1 -> ffn2, blk1)
    float*          XT32P  = (float*) (base + 67108864);     // 16.78 MB (blk1 ffn2 -> blk2 value path)
    int*            IDX    = (int*)   (base + 100663296);    // 1.18 MB  (rescore -> combine)
    float*          G32    = (float*) (base + 33554432);     // 33.55 MB (blk2)
    float*          H32    = (float*) (base + 33554432);     // 16.78 MB (blk2 ffn)
    double*         XN64_2 = XT64;                           // blk2: in-place over XT64 (dead after blk2 norm)
    double*         SQ64_2 = SQ64_1;

    float* fout = (float*)d_out;

    conv1_kernel64<<<dim3(64, 16), 256, 0, stream>>>(ts, conv1_w, conv1_b, H1_64);
    conv2_kernel64<<<dim3(64, 16), 256, 0, stream>>>(H1_64, conv2_w, conv2_b, XT64);

    // ---------- block 1 (f64 value path; indices exact) ----------
    norm_planes_kernel<<<8192, 256, 0, stream>>>(XT64, XH, XM, XN64_1, SQ64_1);
    knn_mfma12_kernel<<<512, 512, 0, stream>>>(XH, XM, CAND);
    rescore5_kernel<<<8192, 256, 0, stream>>>(XN64_1, SQ64_1, CAND, IDX);
    gemm64t_kernel<0><<<dim3(512, 4), 256, 0, stream>>>(
        XT64, gconv_w, nullptr, nullptr, nullptr, G64, nullptr);
    combine64_kernel<<<16384, 256, 0, stream>>>(
        XT64, G64, IDX, gconv_b, gconv_g, gconv_be);
    gemm64t_kernel<1><<<dim3(512, 2), 256, 0, stream>>>(
        XT64, ffn1_w, ffn1_b, ffn1_g, ffn1_be, H64, nullptr);
    gemm64t_kernel<2><<<dim3(512, 2), 256, 0, stream>>>(
        H64, ffn2_w, ffn2_b, ffn2_g, ffn2_be, XT64, XT32P);

    // ---------- block 2 (indices exact via f64; value path f32) ----------
    norm_planes_kernel<<<8192, 256, 0, stream>>>(XT64, XH, XM, XN64_2, SQ64_2);
    knn_mfma12_kernel<<<512, 512, 0, stream>>>(XH, XM, CAND);
    rescore5_kernel<<<8192, 256, 0, stream>>>(XN64_2, SQ64_2, CAND, IDX);
    gemm32f_kernel<0><<<dim3(512, 2), 256, 0, stream>>>(
        XT32P, gconv_w + 32768, nullptr, nullptr, nullptr, G32);
    combine_kernel<<<16384, 256, 0, stream>>>(
        XT32P, G32, IDX, gconv_b + 128, gconv_g + 128, gconv_be + 128, XT32P);
    gemm32f_kernel<1><<<dim3(512, 1), 256, 0, stream>>>(
        XT32P, ffn1_w + 16384, ffn1_b + 128, ffn1_g + 128, ffn1_be + 128, H32);
    gemm32f_kernel<2><<<dim3(512, 1), 256, 0, stream>>>(
        H32, ffn2_w + 16384, ffn2_b + 128, ffn2_g + 128, ffn2_be + 128, fout);
}

// Round 23
// 630.068 us; speedup vs baseline: 1.0228x; 1.0080x over previous
//
#include <hip/hip_runtime.h>
#include <hip/hip_bf16.h>

#define DEV_INLINE __device__ __forceinline__

typedef short s16x8 __attribute__((ext_vector_type(8)));
typedef float f32x4 __attribute__((ext_vector_type(4)));

DEV_INLINE float gelu_exact(float x) {
    return 0.5f * x * (1.0f + erff(x * 0.70710678118654752440f));
}
DEV_INLINE double gelu64(double x) {
    return 0.5 * x * (1.0 + erf(x * 0.70710678118654752440));
}
DEV_INLINE unsigned short f2bf_rne(float f) {
    unsigned u = __float_as_uint(f);
    unsigned r = u + 0x7FFFu + ((u >> 16) & 1u);
    return (unsigned short)(r >> 16);
}
DEV_INLINE float bf2f(unsigned short h) { return __uint_as_float(((unsigned)h) << 16); }

DEV_INLINE void gload_lds16(const void* g, void* l) {
    __builtin_amdgcn_global_load_lds(
        (const __attribute__((address_space(1))) unsigned int*)g,
        (__attribute__((address_space(3))) unsigned int*)l, 16, 0, 0);
}

DEV_INLINE unsigned med3u32(unsigned a, unsigned b, unsigned c) {
    unsigned d;
    asm("v_med3_u32 %0, %1, %2, %3" : "=v"(d) : "v"(a), "v"(b), "v"(c));
    return d;
}

// ---------------- conv1 (f64): ts (16,100,2048) f32 -> relu(causal conv d=1) -> h1 (16,64,2048) f64
__global__ __launch_bounds__(256) void conv1_kernel64(
    const float* __restrict__ x, const float* __restrict__ w,
    const float* __restrict__ bias, double* __restrict__ y)
{
    const int b = blockIdx.y;
    const int t0 = blockIdx.x * 32;
    __shared__ double xs[100][34];
    for (int e = threadIdx.x; e < 100 * 34; e += 256) {
        int i = e / 34, u = e - i * 34;
        int t = t0 - 2 + u;
        xs[i][u] = (t >= 0) ? (double)x[(b * 100 + i) * 2048 + t] : 0.0;
    }
    __syncthreads();
    const int o = threadIdx.x & 63;
    const int ts = (threadIdx.x >> 6) * 8;
    double acc[8];
    double bv = (double)bias[o];
#pragma unroll
    for (int j = 0; j < 8; ++j) acc[j] = bv;
    const float* wo = w + o * 300;
    for (int i = 0; i < 100; ++i) {
        double w0 = (double)wo[i * 3 + 0], w1 = (double)wo[i * 3 + 1], w2 = (double)wo[i * 3 + 2];
#pragma unroll
        for (int j = 0; j < 8; ++j) {
            acc[j] = fma(w0, xs[i][ts + j],
                     fma(w1, xs[i][ts + j + 1],
                     fma(w2, xs[i][ts + j + 2], acc[j])));
        }
    }
#pragma unroll
    for (int j = 0; j < 8; ++j)
        y[(b * 64 + o) * 2048 + t0 + ts + j] = fmax(acc[j], 0.0);
}

// ---------------- conv2 (f64): h1 -> relu(causal conv d=2) -> xt64 (16,2048,128) transposed
__global__ __launch_bounds__(256) void conv2_kernel64(
    const double* __restrict__ x, const float* __restrict__ w,
    const float* __restrict__ bias, double* __restrict__ xt)
{
    const int b = blockIdx.y;
    const int t0 = blockIdx.x * 32;
    __shared__ double xs[64][36];
    for (int e = threadIdx.x; e < 64 * 36; e += 256) {
        int i = e / 36, u = e - i * 36;
        int t = t0 - 4 + u;
        xs[i][u] = (t >= 0) ? x[(b * 64 + i) * 2048 + t] : 0.0;
    }
    __syncthreads();
    const int o = threadIdx.x & 127;
    const int ts = (threadIdx.x >> 7) * 16;
    double acc[16];
    double bv = (double)bias[o];
#pragma unroll
    for (int j = 0; j < 16; ++j) acc[j] = bv;
    const float* wo = w + o * 192;
    for (int i = 0; i < 64; ++i) {
        double w0 = (double)wo[i * 3 + 0], w1 = (double)wo[i * 3 + 1], w2 = (double)wo[i * 3 + 2];
#pragma unroll
        for (int j = 0; j < 16; ++j) {
            acc[j] = fma(w0, xs[i][ts + j],
                     fma(w1, xs[i][ts + j + 2],
                     fma(w2, xs[i][ts + j + 4], acc[j])));
        }
    }
#pragma unroll
    for (int j = 0; j < 16; ++j)
        xt[(size_t)(b * 2048 + t0 + ts + j) * 128 + o] = fmax(acc[j], 0.0);
}

// ---------------- norm+split: xt64 -> f64-normalized rows (XN64, SQ64) + hi/mid bf16 planes
// NOTE: XN64 may alias xt64 (in-place): each element is read only by the thread that writes it.
__global__ __launch_bounds__(256) void norm_planes_kernel(
    const double* __restrict__ xt64, unsigned short* __restrict__ XH,
    unsigned short* __restrict__ XM, double* __restrict__ XN64,
    double* __restrict__ SQ64)
{
    const int row = blockIdx.x * 4 + (threadIdx.x >> 6);
    const int lane = threadIdx.x & 63;
    double v0 = xt64[(size_t)row * 128 + lane * 2];
    double v1 = xt64[(size_t)row * 128 + lane * 2 + 1];
    double s = v0 * v0 + v1 * v1;
#pragma unroll
    for (int off = 32; off > 0; off >>= 1) s += __shfl_xor(s, off);
    double inv = 1.0 / fmax(sqrt(s), 1e-12);
    double n0 = v0 * inv, n1 = v1 * inv;
    XN64[(size_t)row * 128 + lane * 2]     = n0;
    XN64[(size_t)row * 128 + lane * 2 + 1] = n1;
    double q = n0 * n0 + n1 * n1;
#pragma unroll
    for (int off = 32; off > 0; off >>= 1) q += __shfl_xor(q, off);
    if (lane == 0) SQ64[row] = q;
    float x0 = (float)n0, x1 = (float)n1;
    unsigned short h0 = f2bf_rne(x0), h1 = f2bf_rne(x1);
    unsigned short m0 = f2bf_rne(x0 - bf2f(h0)), m1 = f2bf_rne(x1 - bf2f(h1));
    ushort2 hv; hv.x = h0; hv.y = h1;
    ushort2 mv; mv.x = m0; mv.y = m1;
    *(ushort2*)(XH + (size_t)row * 128 + lane * 2) = hv;
    *(ushort2*)(XM + (size_t)row * 128 + lane * 2) = mv;
}

// sorted-insert via med3: for sorted k0>=...>=k8 and candidate c,
// k0' = max(k0,c); ki' = median(k_{i-1}, k_i, c). 9 independent ops.
#define INS9(cc) do { \
    unsigned c_ = (cc); \
    unsigned n0_ = (k0 > c_) ? k0 : c_; \
    unsigned n1_ = med3u32(k0, k1, c_); \
    unsigned n2_ = med3u32(k1, k2, c_); \
    unsigned n3_ = med3u32(k2, k3, c_); \
    unsigned n4_ = med3u32(k3, k4, c_); \
    unsigned n5_ = med3u32(k4, k5, c_); \
    unsigned n6_ = med3u32(k5, k6, c_); \
    unsigned n7_ = med3u32(k6, k7, c_); \
    unsigned n8_ = med3u32(k7, k8, c_); \
    k0 = n0_; k1 = n1_; k2 = n2_; k3 = n3_; k4 = n4_; \
    k5 = n5_; k6 = n6_; k7 = n7_; k8 = n8_; \
} while (0)

// ---------------- knn stage 1 v12: 512 blocks x 512 thr, 32-row tiles, dbuf 32KB,
// full 16-slot XOR swizzle on both write (source col) and read sides.
__global__ __launch_bounds__(512, 4) void knn_mfma12_kernel(
    const unsigned short* __restrict__ XH, const unsigned short* __restrict__ XM,
    int* __restrict__ cand_out)
{
    __shared__ __align__(16) unsigned char smem[32768];  // 2 bufs x (H 8KB | M 8KB)

    const int tid = threadIdx.x, wave = tid >> 6, lane = tid & 63;
    const int bid = blockIdx.x;
    const int j = bid >> 3;                      // 0..63
    const int b = (bid & 7) * 2 + (j >> 5);      // XCD-local batch
    const int ntile = (j & 31) >> 1;             // 0..15
    const int mhalf = j & 1;                     // 0..1
    const int n0 = ntile * 128;
    const int mstart = mhalf * 1024;
    const unsigned short* Hb = XH + (size_t)b * 2048 * 128;
    const unsigned short* Mb = XM + (size_t)b * 2048 * 128;

    s16x8 aH[4], aM[4];
    {
        int arow = n0 + wave * 16 + (lane & 15);
        const unsigned short* hrow = Hb + (size_t)arow * 128;
        const unsigned short* mrow = Mb + (size_t)arow * 128;
        int cb = (lane >> 4) * 8;
#pragma unroll
        for (int s = 0; s < 4; ++s) {
            aH[s] = *(const s16x8*)(hrow + s * 32 + cb);
            aM[s] = *(const s16x8*)(mrow + s * 32 + cb);
        }
    }

    const unsigned short* Pb = (wave >> 2) ? Mb : Hb;
    const unsigned short* gsrc0; const unsigned short* gsrc1;
    {
        int r0 = (wave & 3) * 8 + 0 + (lane >> 4), c0 = (lane & 15) ^ (r0 & 15);
        int r1 = (wave & 3) * 8 + 4 + (lane >> 4), c1 = (lane & 15) ^ (r1 & 15);
        gsrc0 = Pb + (size_t)(mstart + r0) * 128 + c0 * 8;
        gsrc1 = Pb + (size_t)(mstart + r1) * 128 + c1 * 8;
    }
    const unsigned ldsbase = (wave >> 2) * 8192 + (wave & 3) * 2048;

    unsigned k0 = 0, k1 = 0, k2 = 0, k3 = 0, k4 = 0, k5 = 0, k6 = 0, k7 = 0, k8 = 0;

    gload_lds16(gsrc0, smem + ldsbase);
    gload_lds16(gsrc1, smem + ldsbase + 1024);
    __syncthreads();

    int cur = 0;
    for (int t = 0; t < 32; ++t) {
        if (t < 31) {
            size_t go = (size_t)(t + 1) * 32 * 128;
            unsigned lb = (cur ^ 1) * 16384 + ldsbase;
            gload_lds16(gsrc0 + go, smem + lb);
            gload_lds16(gsrc1 + go, smem + lb + 1024);
        }
        const unsigned char* B0 = smem + cur * 16384;
        const unsigned char* B1 = B0 + 8192;
#pragma unroll
        for (int ct = 0; ct < 2; ++ct) {
            f32x4 accA; accA[0] = 0.f; accA[1] = 0.f; accA[2] = 0.f; accA[3] = 0.f;
            f32x4 accB; accB[0] = 0.f; accB[1] = 0.f; accB[2] = 0.f; accB[3] = 0.f;
            int r = ct * 16 + (lane & 15);
#pragma unroll
            for (int s = 0; s < 4; ++s) {
                int off = r * 256 + (((s * 64) + ((lane >> 4) * 16)) ^ ((r & 15) << 4));
                s16x8 bH = *(const s16x8*)(B0 + off);
                s16x8 bM = *(const s16x8*)(B1 + off);
                accA = __builtin_amdgcn_mfma_f32_16x16x32_bf16(bH, aH[s], accA, 0, 0, 0);
                accB = __builtin_amdgcn_mfma_f32_16x16x32_bf16(bM, aH[s], accB, 0, 0, 0);
                accB = __builtin_amdgcn_mfma_f32_16x16x32_bf16(bH, aM[s], accB, 0, 0, 0);
            }
            const unsigned Lb = (unsigned)(255 - (t * 8 + ct * 4));
            unsigned key0 = (__float_as_uint(accA[0] + accB[0] + 2.0f) & 0xFFFFFF00u) | (Lb - 0u);
            unsigned key1 = (__float_as_uint(accA[1] + accB[1] + 2.0f) & 0xFFFFFF00u) | (Lb - 1u);
            unsigned key2 = (__float_as_uint(accA[2] + accB[2] + 2.0f) & 0xFFFFFF00u) | (Lb - 2u);
            unsigned key3 = (__float_as_uint(accA[3] + accB[3] + 2.0f) & 0xFFFFFF00u) | (Lb - 3u);
            INS9(key0);
            INS9(key1);
            INS9(key2);
            INS9(key3);
        }
        __syncthreads();
        cur ^= 1;
    }

    const int g = lane >> 4;
    const int row = b * 2048 + n0 + wave * 16 + (lane & 15);
#pragma unroll
    for (int pass = 0; pass < 16; ++pass) {
        unsigned mykey = k0;
        int L = 255 - (int)(mykey & 0xFFu);
        int mym = mstart + (L >> 3) * 32 + ((L >> 2) & 1) * 16 + g * 4 + (L & 3);
        unsigned bkey = mykey; int bm = mym;
        unsigned ok = (unsigned)__shfl_xor((int)bkey, 16); int om = __shfl_xor(bm, 16);
        bool tk = (ok > bkey) || (ok == bkey && om < bm);
        bkey = tk ? ok : bkey; bm = tk ? om : bm;
        ok = (unsigned)__shfl_xor((int)bkey, 32); om = __shfl_xor(bm, 32);
        tk = (ok > bkey) || (ok == bkey && om < bm);
        bkey = tk ? ok : bkey; bm = tk ? om : bm;
        if (mym == bm) {
            k0 = k1; k1 = k2; k2 = k3; k3 = k4; k4 = k5; k5 = k6; k6 = k7; k7 = k8; k8 = 0;
        }
        if (g == (pass & 3)) cand_out[(size_t)row * 32 + mhalf * 16 + pass] = bm;
    }
}

// ---------------- knn stage 2 v5 (f64): coalesced rescore + rank-by-count selection.
// (256,4): VGPR cap 128; ~60 live regs, NO spill (round-18 lesson).
__global__ __launch_bounds__(256, 4) void rescore5_kernel(
    const double* __restrict__ XN64, const double* __restrict__ SQ64,
    const int* __restrict__ cand, int* __restrict__ idx_out)
{
    const int wid = threadIdx.x >> 6, lane = threadIdx.x & 63;
    const int wb = (blockIdx.x & 7) * 1024 + (blockIdx.x >> 3);  // 8192 blocks, bijective
    const int n = wb * 4 + wid;
    const int b = n >> 11;
    const int g = lane >> 4, e = lane & 15;
    const double* Xb = XN64 + (size_t)(b * 2048) * 128;
    const double* SQb = SQ64 + (size_t)b * 2048;

    double2 xq[4];
    const double* xqp = XN64 + (size_t)n * 128;
#pragma unroll
    for (int it = 0; it < 4; ++it)
        xq[it] = *(const double2*)(xqp + it * 32 + e * 2);

    int mi[8];
    double s[8];
#pragma unroll
    for (int bb = 0; bb < 8; ++bb) {
        int m = cand[(size_t)n * 32 + bb * 4 + g];
        mi[bb] = m;
        const double* xm = Xb + (size_t)m * 128;
        double a0 = 0.0, a1 = 0.0;
#pragma unroll
        for (int it = 0; it < 4; ++it) {
            double2 v = *(const double2*)(xm + it * 32 + e * 2);
            a0 = fma(xq[it].x, v.x, a0);
            a1 = fma(xq[it].y, v.y, a1);
        }
        s[bb] = a0 + a1;
    }
#pragma unroll
    for (int bb = 0; bb < 8; ++bb) {
        double d = s[bb];
        d += __shfl_xor(d, 1);
        d += __shfl_xor(d, 2);
        d += __shfl_xor(d, 4);
        d += __shfl_xor(d, 8);
        s[bb] = 2.0 * d - SQb[mi[bb]];
    }
    double mys = s[0]; int mym = mi[0];
#pragma unroll
    for (int q = 1; q < 8; ++q) {
        bool p = (e == q);
        mys = p ? s[q] : mys;
        mym = p ? mi[q] : mym;
    }
    int cnt = 0;
#pragma unroll
    for (int bb = 0; bb < 8; ++bb) {
        cnt += ((s[bb] > mys) || (s[bb] == mys && mi[bb] < mym)) ? 1 : 0;
        double a16 = __shfl_xor(s[bb], 16); int m16 = __shfl_xor(mi[bb], 16);
        cnt += ((a16 > mys) || (a16 == mys && m16 < mym)) ? 1 : 0;
        double a32 = __shfl_xor(s[bb], 32); int m32 = __shfl_xor(mi[bb], 32);
        cnt += ((a32 > mys) || (a32 == mys && m32 < mym)) ? 1 : 0;
        double a48 = __shfl_xor(a16, 32);  int m48 = __shfl_xor(m16, 32);
        cnt += ((a48 > mys) || (a48 == mys && m48 < mym)) ? 1 : 0;
    }
    if (e < 8 && cnt < 9)
        idx_out[(size_t)n * 9 + cnt] = mym;
}

// ---------------- f64 GEMM v2 (K=128 in 4 chunks of 32 -> 34.8 KB LDS, 4 blocks/CU,
// vectorized double2/float2 staging, template MODE).
template<int MODE>
__global__ __launch_bounds__(256, 4) void gemm64t_kernel(
    const double* __restrict__ A, const float* __restrict__ W,
    const float* __restrict__ bias, const float* __restrict__ gamma,
    const float* __restrict__ beta, double* __restrict__ out,
    float* __restrict__ out32)
{
    __shared__ double As[64][34];
    __shared__ double Ws[64][34];
    const int bx = (blockIdx.x & 7) * (gridDim.x >> 3) + (blockIdx.x >> 3);
    const int m0 = bx * 64;
    const int j0 = blockIdx.y * 64;
    const int ri = threadIdx.x >> 4, ci = threadIdx.x & 15;
    double acc[4][4];
#pragma unroll
    for (int u = 0; u < 4; ++u)
#pragma unroll
        for (int v = 0; v < 4; ++v) acc[u][v] = 0.0;

    for (int k0 = 0; k0 < 128; k0 += 32) {
        __syncthreads();
        for (int e = threadIdx.x; e < 64 * 16; e += 256) {
            int r = e >> 4, c2 = (e & 15) * 2;
            *(double2*)&As[r][c2] = *(const double2*)(A + (size_t)(m0 + r) * 128 + k0 + c2);
            int jw = j0 + r;
            float2 wv;
            if (MODE == 0) {
                wv = (jw < 128) ? *(const float2*)(W + jw * 256 + k0 + c2)
                                : *(const float2*)(W + (jw - 128) * 256 + 128 + k0 + c2);
            } else {
                wv = *(const float2*)(W + jw * 128 + k0 + c2);
            }
            double2 wd; wd.x = (double)wv.x; wd.y = (double)wv.y;
            *(double2*)&Ws[r][c2] = wd;
        }
        __syncthreads();
        for (int c = 0; c < 32; c += 2) {
            double a0[4], a1[4], w0[4], w1[4];
#pragma unroll
            for (int u = 0; u < 4; ++u) { a0[u] = As[ri + 16 * u][c]; a1[u] = As[ri + 16 * u][c + 1]; }
#pragma unroll
            for (int v = 0; v < 4; ++v) { w0[v] = Ws[ci + 16 * v][c]; w1[v] = Ws[ci + 16 * v][c + 1]; }
#pragma unroll
            for (int u = 0; u < 4; ++u)
#pragma unroll
                for (int v = 0; v < 4; ++v)
                    acc[u][v] = fma(a1[u], w1[v], fma(a0[u], w0[v], acc[u][v]));
        }
    }
#pragma unroll
    for (int u = 0; u < 4; ++u) {
        int row = m0 + ri + 16 * u;
#pragma unroll
        for (int v = 0; v < 4; ++v) {
            int jl = ci + 16 * v;
            double val = acc[u][v];
            if (MODE == 0) {
                out[(size_t)row * 256 + j0 + jl] = val;
            } else {
                int jg = j0 + jl;
                double z = (val + (double)bias[jg]) * (double)gamma[jg] + (double)beta[jg];
                if (MODE == 1) {
                    out[(size_t)row * 128 + jg] = gelu64(z);
                } else {
                    out[(size_t)row * 128 + jg] = z;
                    out32[(size_t)row * 128 + jg] = (float)z;
                }
            }
        }
    }
}

// ---------------- combine64 v2 (in-place residual), XCD-chunked, 2-endpoint gelu.
__global__ __launch_bounds__(256) void combine64_kernel(
    double* __restrict__ xt, const double* __restrict__ G,
    const int* __restrict__ idx, const float* __restrict__ bias,
    const float* __restrict__ gamma, const float* __restrict__ beta)
{
    const int wb = (blockIdx.x & 7) * 2048 + (blockIdx.x >> 3);
    const int row = wb * 2 + (threadIdx.x >> 7);
    const int o = threadIdx.x & 127;
    const int b = row >> 11;
    const double* Gb = G + (size_t)(b * 2048) * 256;
    const int* id9 = idx + (size_t)row * 9;
    double g1  = G[(size_t)row * 256 + o];
    double g2i = G[(size_t)row * 256 + 128 + o];
    double base = g1 + (double)bias[o] - g2i;
    double gm = (double)gamma[o], bt = (double)beta[o];
    double g2mx = -1.0e300, g2mn = 1.0e300;
#pragma unroll
    for (int k = 0; k < 9; ++k) {
        int jn = id9[k];
        double g2 = Gb[(size_t)jn * 256 + 128 + o];
        g2mx = fmax(g2mx, g2);
        g2mn = fmin(g2mn, g2);
    }
    double z1 = (base + g2mx) * gm + bt;
    double z2 = (base + g2mn) * gm + bt;
    double mx = fmax(gelu64(z1), gelu64(z2));
    xt[(size_t)row * 128 + o] += mx;
}

// ---------------- f32 GEMM v3 (block-2 value path): BM=64/BN=128/BK=32,
// 27.6 KB LDS, float4 staging, acc[4][8], template MODE, XCD-chunked.
template<int MODE>
__global__ __launch_bounds__(256, 4) void gemm32f_kernel(
    const float* __restrict__ A, const float* __restrict__ W,
    const float* __restrict__ bias, const float* __restrict__ gamma,
    const float* __restrict__ beta, float* __restrict__ out)
{
    __shared__ float As[64][36];
    __shared__ float Ws[128][36];
    const int bx = (blockIdx.x & 7) * (gridDim.x >> 3) + (blockIdx.x >> 3);
    const int m0 = bx * 64;
    const int j0 = blockIdx.y * 128;
    const int ri = threadIdx.x >> 4, ci = threadIdx.x & 15;
    float acc[4][8];
#pragma unroll
    for (int u = 0; u < 4; ++u)
#pragma unroll
        for (int v = 0; v < 8; ++v) acc[u][v] = 0.0f;

    for (int k0 = 0; k0 < 128; k0 += 32) {
        __syncthreads();
        for (int e = threadIdx.x; e < 64 * 8; e += 256) {
            int r = e >> 3, q = (e & 7) * 4;
            *(float4*)&As[r][q] = *(const float4*)(A + (size_t)(m0 + r) * 128 + k0 + q);
        }
        for (int e = threadIdx.x; e < 128 * 8; e += 256) {
            int r = e >> 3, q = (e & 7) * 4;
            const float* src;
            if (MODE == 0) {
                int jw = j0 + r;
                src = (jw < 128) ? (W + jw * 256 + k0 + q) : (W + (jw - 128) * 256 + 128 + k0 + q);
            } else {
                src = W + r * 128 + k0 + q;
            }
            *(float4*)&Ws[r][q] = *(const float4*)src;
        }
        __syncthreads();
        for (int c = 0; c < 32; c += 4) {
            float4 a4[4];
#pragma unroll
            for (int u = 0; u < 4; ++u) a4[u] = *(const float4*)&As[ri + 16 * u][c];
#pragma unroll
            for (int v = 0; v < 8; ++v) {
                float4 w4 = *(const float4*)&Ws[ci + 16 * v][c];
#pragma unroll
                for (int u = 0; u < 4; ++u) {
                    acc[u][v] = fmaf(a4[u].x, w4.x, fmaf(a4[u].y, w4.y,
                                fmaf(a4[u].z, w4.z, fmaf(a4[u].w, w4.w, acc[u][v]))));
                }
            }
        }
    }
#pragma unroll
    for (int u = 0; u < 4; ++u) {
        int row = m0 + ri + 16 * u;
#pragma unroll
        for (int v = 0; v < 8; ++v) {
            int jn = ci + 16 * v;
            float val = acc[u][v];
            if (MODE == 0) {
                out[(size_t)row * 256 + j0 + jn] = val;
            } else if (MODE == 1) {
                float z = (val + bias[jn]) * gamma[jn] + beta[jn];
                out[(size_t)row * 128 + jn] = gelu_exact(z);
            } else {
                float z = (val + bias[jn]) * gamma[jn] + beta[jn];
                out[(size_t)row * 128 + jn] = z;
            }
        }
    }
}

// ---------------- combine f32 v2 (block 2; in-place safe), XCD-chunked, 2-endpoint gelu
__global__ __launch_bounds__(256) void combine_kernel(
    const float* __restrict__ xt, const float* __restrict__ G,
    const int* __restrict__ idx, const float* __restrict__ bias,
    const float* __restrict__ gamma, const float* __restrict__ beta,
    float* __restrict__ xt2)
{
    const int wb = (blockIdx.x & 7) * 2048 + (blockIdx.x >> 3);
    const int row = wb * 2 + (threadIdx.x >> 7);
    const int o = threadIdx.x & 127;
    const int b = row >> 11;
    const float* Gb = G + (size_t)(b * 2048) * 256;
    const int* id9 = idx + (size_t)row * 9;
    float g1  = G[(size_t)row * 256 + o];
    float g2i = G[(size_t)row * 256 + 128 + o];
    float base = g1 + bias[o] - g2i;
    float gm = gamma[o], bt = beta[o];
    float g2mx = -3.4e38f, g2mn = 3.4e38f;
#pragma unroll
    for (int k = 0; k < 9; ++k) {
        int jn = id9[k];
        float g2 = Gb[(size_t)jn * 256 + 128 + o];
        g2mx = fmaxf(g2mx, g2);
        g2mn = fminf(g2mn, g2);
    }
    float z1 = (base + g2mx) * gm + bt;
    float z2 = (base + g2mn) * gm + bt;
    float mx = fmaxf(gelu_exact(z1), gelu_exact(z2));
    xt2[(size_t)row * 128 + o] = xt[(size_t)row * 128 + o] + mx;
}

extern "C" void kernel_launch(void* const* d_in, const int* in_sizes, int n_in,
                              void* d_out, int out_size, void* d_ws, size_t ws_size,
                              hipStream_t stream)
{
    const float* ts       = (const float*)d_in[0];
    const float* conv1_w  = (const float*)d_in[1];
    const float* conv1_b  = (const float*)d_in[2];
    const float* conv2_w  = (const float*)d_in[3];
    const float* conv2_b  = (const float*)d_in[4];
    const float* gconv_w  = (const float*)d_in[5];
    const float* gconv_b  = (const float*)d_in[6];
    const float* gconv_g  = (const float*)d_in[7];
    const float* gconv_be = (const float*)d_in[8];
    const float* ffn1_w   = (const float*)d_in[9];
    const float* ffn1_b   = (const float*)d_in[10];
    const float* ffn1_g   = (const float*)d_in[11];
    const float* ffn1_be  = (const float*)d_in[12];
    const float* ffn2_w   = (const float*)d_in[13];
    const float* ffn2_b   = (const float*)d_in[14];
    const float* ffn2_g   = (const float*)d_in[15];
    const float* ffn2_be  = (const float*)d_in[16];
    (void)in_sizes; (void)n_in; (void)out_size; (void)ws_size;

    // ---- workspace layout (byte offsets), lifetime-overlaid; peak ~101.8 MB ----
    char* base = (char*)d_ws;
    double*         XT64   = (double*)(base + 0);            // 33.55 MB
    double*         H1_64  = (double*)(base + 33554432);     // 16.78 MB (conv phase only)
    unsigned short* XH     = (unsigned short*)(base + 33554432); // 8.39 MB (norm -> knn)
    unsigned short* XM     = (unsigned short*)(base + 41943040); // 8.39 MB (norm -> knn)
    int*            CAND   = (int*)   (base + 50331648);     // 4.19 MB  (knn -> rescore; 32/row)
    double*         XN64_1 = (double*)(base + 54525952);     // 33.55 MB (blk1 norm -> rescore; dies before G64 use)
    double*         SQ64_1 = (double*)(base + 88080384);     // 0.26 MB
    double*         G64    = (double*)(base + 33554432);     // 67.11 MB (gemm0 -> combine, blk1)
    double*         H64    = (double*)(base + 33554432);     // 33.55 MB (ffn1 -> ffn2, blk1)
    float*          XT32P  = (float*) (base + 67108864);     // 16.78 MB (blk1 ffn2 -> blk2 value path)
    int*            IDX    = (int*)   (base + 100663296);    // 1.18 MB  (rescore -> combine)
    float*          G32    = (float*) (base + 33554432);     // 33.55 MB (blk2)
    float*          H32    = (float*) (base + 33554432);     // 16.78 MB (blk2 ffn)
    double*         XN64_2 = XT64;                           // blk2: in-place over XT64 (dead after blk2 norm)
    double*         SQ64_2 = SQ64_1;

    float* fout = (float*)d_out;

    conv1_kernel64<<<dim3(64, 16), 256, 0, stream>>>(ts, conv1_w, conv1_b, H1_64);
    conv2_kernel64<<<dim3(64, 16), 256, 0, stream>>>(H1_64, conv2_w, conv2_b, XT64);

    // ---------- block 1 (f64 value path; indices exact) ----------
    norm_planes_kernel<<<8192, 256, 0, stream>>>(XT64, XH, XM, XN64_1, SQ64_1);
    knn_mfma12_kernel<<<512, 512, 0, stream>>>(XH, XM, CAND);
    rescore5_kernel<<<8192, 256, 0, stream>>>(XN64_1, SQ64_1, CAND, IDX);
    gemm64t_kernel<0><<<dim3(512, 4), 256, 0, stream>>>(
        XT64, gconv_w, nullptr, nullptr, nullptr, G64, nullptr);
    combine64_kernel<<<16384, 256, 0, stream>>>(
        XT64, G64, IDX, gconv_b, gconv_g, gconv_be);
    gemm64t_kernel<1><<<dim3(512, 2), 256, 0, stream>>>(
        XT64, ffn1_w, ffn1_b, ffn1_g, ffn1_be, H64, nullptr);
    gemm64t_kernel<2><<<dim3(512, 2), 256, 0, stream>>>(
        H64, ffn2_w, ffn2_b, ffn2_g, ffn2_be, XT64, XT32P);

    // ---------- block 2 (indices exact via f64; value path f32) ----------
    norm_planes_kernel<<<8192, 256, 0, stream>>>(XT64, XH, XM, XN64_2, SQ64_2);
    knn_mfma12_kernel<<<512, 512, 0, stream>>>(XH, XM, CAND);
    rescore5_kernel<<<8192, 256, 0, stream>>>(XN64_2, SQ64_2, CAND, IDX);
    gemm32f_kernel<0><<<dim3(512, 2), 256, 0, stream>>>(
        XT32P, gconv_w + 32768, nullptr, nullptr, nullptr, G32);
    combine_kernel<<<16384, 256, 0, stream>>>(
        XT32P, G32, IDX, gconv_b + 128, gconv_g + 128, gconv_be + 128, XT32P);
    gemm32f_kernel<1><<<dim3(512, 1), 256, 0, stream>>>(
        XT32P, ffn1_w + 16384, ffn1_b + 128, ffn1_g + 128, ffn1_be + 128, H32);
    gemm32f_kernel<2><<<dim3(512, 1), 256, 0, stream>>>(
        H32, ffn2_w + 16384, ffn2_b + 128, ffn2_g + 128, ffn2_be + 128, fout);
}